// Round 12
// baseline (356.794 us; speedup 1.0000x reference)
//
#include <hip/hip_runtime.h>

// SparseMinCostFlow — SINGLE mega-dispatch: sorts ∥ 256-wide chain → direct scatter.
// N=8192, E=262144, 10 flow iters, dense NxN fp32 out (256 MB).
//
// r11 accounting: total 343 = harness poison fills (~204, fixed) + mega ~139
// (sort/waits ~25 + chain ~30 + scatter ~60). Scatter's 60 vs 41 floor =
// 64 block-barriers + 3x32KB LDS passes per row between store bursts.
// r12: scatter WITHOUT the LDS image: stream 1MB zeros over my 32 rows
// (coalesced, no barriers) -> __syncthreads (vmcnt(0) drain: zeros at
// coherence point) -> 1-2 premultiplied global atomicAdds per thread
// (262k total, ~distinct lines; r0's scatter_final proved ~30us). Deletes
// all per-row barriers and LDS traffic. Duplicate (r,c) summed by atomics.
//
//  blocks 0..63  : col-sort (256 buckets, col>>5) -> flagsE -> chain -> scatter
//  blocks 64..127: row-sort (256 groups, row>>5) -> flagsR2 -> join chain
//  blocks 128..255: park until flagsE -> chain -> scatter
//  chain: all 256 blocks; block owns 32 cols; 1-2 reg edges/thread; per stage
//    adj GATHERS (agent) + 32-col LDS acc + 32-float publish + 256-party barrier.
// Uniform pre-scatter prereqs (r7 lesson): stage-9 256-party barrier (adj9f)
// + all-64 flagsR2 (se2/gstart). All cross-block ws data agent-scope (ws is
// re-poisoned each iter => plain reads could hit stale 0xAA in L2).
// Grid=256=#CUs, LDS ~67KB => all 256 co-resident (required for flag barriers).

#define NN 8192
#define EE 262144
#define THREADS 1024
#define SORTB 64                 // blocks per sort team
#define EPB (EE / SORTB)         // 4096 edges per sort block (4/thread)
#define NB 256                   // buckets = groups = chain blocks
#define CPB (NN / NB)            // 32 cols per chain block
#define GROWS 32                 // rows per scatter group
#define NBLK 256
#define MAGIC 0x5CA1AB1Eu        // != 0xAAAAAAAA ws poison, != 0

typedef unsigned long long u64;

#define LOAD_AU(p)    __hip_atomic_load((p),  __ATOMIC_RELAXED, __HIP_MEMORY_SCOPE_AGENT)
#define STORE_AU(p,v) __hip_atomic_store((p), (v), __ATOMIC_RELAXED, __HIP_MEMORY_SCOPE_AGENT)

// LDS arena: one member live at a time (phases separated by barriers/syncs).
union SM {
    struct { unsigned cnt[SORTB * NB]; unsigned hist[NB]; unsigned bst[NB + 1];
             unsigned offs[NB]; } so;                                  // ~67 KB
    struct { float acc[CPB]; float dem[CPB]; } c;                      // 256 B
};

// nblk(<=64)-party: set own word + poll (caller __syncthreads first: vmcnt drain).
__device__ __forceinline__ void flag_barrier_n(unsigned* fl, int idx, int tid, int nblk) {
    if (tid == 0) STORE_AU(&fl[idx], MAGIC);
    asm volatile("" ::: "memory");
    if (tid < 64) {
        for (;;) {
            unsigned f = (tid < nblk) ? LOAD_AU(&fl[tid]) : MAGIC;
            if (__all(f == MAGIC)) break;
            __builtin_amdgcn_s_sleep(2);
        }
    }
    asm volatile("" ::: "memory");
    __syncthreads();
}

// 256-party: set own word + poll 4 words/lane.
__device__ __forceinline__ void flag_barrier_256(unsigned* fl, int idx, int tid) {
    if (tid == 0) STORE_AU(&fl[idx], MAGIC);
    asm volatile("" ::: "memory");
    if (tid < 64) {
        for (;;) {
            unsigned a = LOAD_AU(&fl[tid]);
            unsigned b = LOAD_AU(&fl[tid + 64]);
            unsigned c = LOAD_AU(&fl[tid + 128]);
            unsigned d = LOAD_AU(&fl[tid + 192]);
            if (__all(a == MAGIC && b == MAGIC && c == MAGIC && d == MAGIC)) break;
            __builtin_amdgcn_s_sleep(2);
        }
    }
    asm volatile("" ::: "memory");
    __syncthreads();
}

// passive wait on nblk(<=64) words. SLP: s_sleep ticks, compile-time literal.
template <int SLP>
__device__ __forceinline__ void wait_flags_n(unsigned* fl, int tid, int nblk) {
    if (tid < 64) {
        for (;;) {
            unsigned f = (tid < nblk) ? LOAD_AU(&fl[tid]) : MAGIC;
            if (__all(f == MAGIC)) break;
            __builtin_amdgcn_s_sleep(SLP);
        }
    }
    asm volatile("" ::: "memory");
    __syncthreads();
}

__global__ void __launch_bounds__(THREADS) mega(
        const float* __restrict__ values, const float* __restrict__ dem,
        const int* __restrict__ rows, const int* __restrict__ cols,
        u64* __restrict__ se,        // EE col-sorted: row13 | coff5<<13 | v<<32
        u64* __restrict__ se2,       // EE row-sorted: col13 | rl5<<13  | v<<32
        float* __restrict__ adjF,    // 9*NN floats (slots 1..8)
        float* __restrict__ adj9f,   // NN floats (= A10)
        unsigned* __restrict__ cnt,  // SORTB*NB
        unsigned* __restrict__ cnt2, // SORTB*NB
        unsigned* __restrict__ bstart,   // NB+1
        unsigned* __restrict__ gstart,   // NB+1
        unsigned* __restrict__ flagsC, unsigned* __restrict__ flagsR,
        unsigned* __restrict__ flagsE, unsigned* __restrict__ flagsR2,
        unsigned* __restrict__ flagsK,   // 9*NB
        float* __restrict__ out) {
    __shared__ SM sm;
    __shared__ float a9[GROWS];
    const int bid = blockIdx.x, tid = threadIdx.x;

    if (bid < SORTB) {
        // ============ col-sort team: bucket = col>>5 (256 buckets) ============
        if (tid < NB) sm.so.hist[tid] = 0;
        __syncthreads();
        const int4* c4 = (const int4*)(cols + bid * EPB);
        int4 ca = c4[tid];                            // 4 edges/thread
        atomicAdd(&sm.so.hist[ca.x >> 5], 1u);  atomicAdd(&sm.so.hist[ca.y >> 5], 1u);
        atomicAdd(&sm.so.hist[ca.z >> 5], 1u);  atomicAdd(&sm.so.hist[ca.w >> 5], 1u);
        __syncthreads();
        if (tid < NB) STORE_AU(&cnt[bid * NB + tid], sm.so.hist[tid]);
        __syncthreads();                              // drain cnt
        flag_barrier_n(flagsC, bid, tid, SORTB);

        #pragma unroll
        for (int j = 0; j < (SORTB * NB) / THREADS; ++j)
            sm.so.cnt[tid + j * THREADS] = LOAD_AU(&cnt[tid + j * THREADS]);
        __syncthreads();
        if (tid < NB) {
            unsigned t = 0;
            for (int b = 0; b < SORTB; ++b) t += sm.so.cnt[b * NB + tid];
            sm.so.hist[tid] = t;
        }
        __syncthreads();
        if (tid == 0) {
            unsigned run = 0;
            for (int k = 0; k < NB; ++k) { sm.so.bst[k] = run; run += sm.so.hist[k]; }
            sm.so.bst[NB] = run;
        }
        __syncthreads();
        if (tid < NB) {
            unsigned off = sm.so.bst[tid];
            for (int b = 0; b < bid; ++b) off += sm.so.cnt[b * NB + tid];
            sm.so.offs[tid] = off;
        }
        if (bid == 0 && tid <= NB) STORE_AU(&bstart[tid], sm.so.bst[tid]);
        __syncthreads();

        {   // push: meta = row | (col&31)<<13, value hi32
            const int4*   r4 = (const int4*)(rows + bid * EPB);
            const float4* v4 = (const float4*)(values + bid * EPB);
            int4 ra = r4[tid];  float4 va = v4[tid];
            #define PUSHC(R, C, V) do {                                        \
                unsigned dst_ = atomicAdd(&sm.so.offs[(C) >> 5], 1u);          \
                u64 w_ = (unsigned)((R) | (((C) & 31) << 13))                  \
                       | ((u64)__float_as_uint(V) << 32);                      \
                STORE_AU(&se[dst_], w_);                                       \
            } while (0)
            PUSHC(ra.x, ca.x, va.x);  PUSHC(ra.y, ca.y, va.y);
            PUSHC(ra.z, ca.z, va.z);  PUSHC(ra.w, ca.w, va.w);
            #undef PUSHC
        }
        __syncthreads();                              // drain se + bstart
        flag_barrier_n(flagsE, bid, tid, SORTB);      // col-sort complete
    } else if (bid < 2 * SORTB) {
        // ============ row-sort team: group = row>>5 (256 groups) ============
        const int b2 = bid - SORTB;
        if (tid < NB) sm.so.hist[tid] = 0;
        __syncthreads();
        const int4* r4 = (const int4*)(rows + b2 * EPB);
        int4 ra = r4[tid];
        atomicAdd(&sm.so.hist[ra.x >> 5], 1u);  atomicAdd(&sm.so.hist[ra.y >> 5], 1u);
        atomicAdd(&sm.so.hist[ra.z >> 5], 1u);  atomicAdd(&sm.so.hist[ra.w >> 5], 1u);
        __syncthreads();
        if (tid < NB) STORE_AU(&cnt2[b2 * NB + tid], sm.so.hist[tid]);
        __syncthreads();
        flag_barrier_n(flagsR, b2, tid, SORTB);

        #pragma unroll
        for (int j = 0; j < (SORTB * NB) / THREADS; ++j)
            sm.so.cnt[tid + j * THREADS] = LOAD_AU(&cnt2[tid + j * THREADS]);
        __syncthreads();
        if (tid < NB) {
            unsigned t = 0;
            for (int b = 0; b < SORTB; ++b) t += sm.so.cnt[b * NB + tid];
            sm.so.hist[tid] = t;
        }
        __syncthreads();
        if (tid == 0) {
            unsigned run = 0;
            for (int k = 0; k < NB; ++k) { sm.so.bst[k] = run; run += sm.so.hist[k]; }
            sm.so.bst[NB] = run;
        }
        __syncthreads();
        if (tid < NB) {
            unsigned off = sm.so.bst[tid];
            for (int b = 0; b < b2; ++b) off += sm.so.cnt[b * NB + tid];
            sm.so.offs[tid] = off;
        }
        if (b2 == 0 && tid <= NB) STORE_AU(&gstart[tid], sm.so.bst[tid]);
        __syncthreads();

        {   // push: meta = col | (row&31)<<13, value hi32
            const int4*   c4 = (const int4*)(cols + b2 * EPB);
            const float4* v4 = (const float4*)(values + b2 * EPB);
            int4 ca = c4[tid];  float4 va = v4[tid];
            #define PUSHR(R, C, V) do {                                        \
                unsigned dst_ = atomicAdd(&sm.so.offs[(R) >> 5], 1u);          \
                u64 w_ = (unsigned)((C) | (((R) & 31) << 13))                  \
                       | ((u64)__float_as_uint(V) << 32);                      \
                STORE_AU(&se2[dst_], w_);                                      \
            } while (0)
            PUSHR(ra.x, ca.x, va.x);  PUSHR(ra.y, ca.y, va.y);
            PUSHR(ra.z, ca.z, va.z);  PUSHR(ra.w, ca.w, va.w);
            #undef PUSHR
        }
        __syncthreads();                              // drain se2 + gstart
        if (tid == 0) STORE_AU(&flagsR2[b2], MAGIC);
        asm volatile("" ::: "memory");
        wait_flags_n<4>(flagsE, tid, SORTB);          // then join the chain
    } else {
        // ============ parked until col-sort done ============
        wait_flags_n<8>(flagsE, tid, SORTB);
    }

    // ================= chain: ALL 256 blocks, block owns bucket `bid` =======
    const int bs = (int)LOAD_AU(&bstart[bid]);
    const int be = (int)LOAD_AU(&bstart[bid + 1]);
    const int ne = be - bs;
    u64 e0 = 0, e1 = 0;                               // ~1024 edges -> 1-2 regs
    if (tid < ne)           e0 = LOAD_AU(&se[bs + tid]);
    if (THREADS + tid < ne) e1 = LOAD_AU(&se[bs + THREADS + tid]);
    if (tid < CPB) sm.c.dem[tid] = dem[bid * CPB + tid];

    for (int s = 1; s <= 9; ++s) {
        if (tid < CPB) sm.c.acc[tid] = 0.f;
        __syncthreads();

        #define EDGE(W) do {                                                   \
            unsigned m_ = (unsigned)(W);                                       \
            float v_ = __uint_as_float((unsigned)((W) >> 32));                 \
            int r_ = m_ & (NN - 1);                                            \
            float a_ = (s == 1) ? fmaxf(-dem[r_], 0.f)                         \
                                : LOAD_AU(&adjF[(size_t)(s - 1) * NN + r_]);   \
            atomicAdd(&sm.c.acc[(m_ >> 13) & 31], v_ * a_);                    \
        } while (0)
        if (tid < ne)           EDGE(e0);
        if (THREADS + tid < ne) EDGE(e1);
        for (int i = bs + 2 * THREADS + tid; i < be; i += THREADS) {  // ~never
            u64 w = LOAD_AU(&se[i]);
            EDGE(w);
        }
        #undef EDGE
        __syncthreads();

        if (tid < CPB) {
            float r = fmaxf(sm.c.acc[tid] - sm.c.dem[tid], 0.f);
            if (s < 9) STORE_AU(&adjF[(size_t)s * NN + bid * CPB + tid], r);
            else       STORE_AU(&adj9f[bid * CPB + tid], r);
        }
        __syncthreads();                              // drain publish
        flag_barrier_256(flagsK + (s - 1) * NB, bid, tid);
    }
    // stage-9 barrier == all adj9f visible. Uniform last prereq:
    wait_flags_n<2>(flagsR2, tid, SORTB);             // se2/gstart (long ready)

    // ====== scatter v2: zero-stream my 32 rows + direct global atomics ======
    {
        const int g = bid;
        const unsigned gs = LOAD_AU(&gstart[g]), ge = LOAD_AU(&gstart[g + 1]);
        if (tid < GROWS) a9[tid] = LOAD_AU(&adj9f[g * GROWS + tid]);
        __syncthreads();                              // a9 visible block-wide

        // issue my edge loads early (overlap with zero stream)
        const unsigned i0 = gs + tid, i1 = gs + tid + THREADS;
        u64 w0 = 0, w1 = 0;
        if (i0 < ge) w0 = LOAD_AU(&se2[i0]);
        if (i1 < ge) w1 = LOAD_AU(&se2[i1]);

        // stream 1 MB of zeros over rows [g*32, g*32+32) — coalesced float4,
        // no barriers; aggregate across 256 blocks = 256 MB @ HBM BW
        float* ob = out + (size_t)g * GROWS * NN;
        float4* oz = (float4*)ob;
        const float4 z4 = make_float4(0.f, 0.f, 0.f, 0.f);
        #pragma unroll 4
        for (int k = 0; k < (GROWS * NN / 4) / THREADS; ++k)
            oz[tid + k * THREADS] = z4;

        // __syncthreads emits s_waitcnt vmcnt(0) before s_barrier: my zeros
        // (and edge loads) are at the coherence point before any atomic fires.
        __syncthreads();

        if (i0 < ge) {
            unsigned m = (unsigned)w0;
            float v = __uint_as_float((unsigned)(w0 >> 32)) * a9[(m >> 13) & 31];
            atomicAdd(&ob[(size_t)((m >> 13) & 31) * NN + (m & (NN - 1))], v);
        }
        if (i1 < ge) {
            unsigned m = (unsigned)w1;
            float v = __uint_as_float((unsigned)(w1 >> 32)) * a9[(m >> 13) & 31];
            atomicAdd(&ob[(size_t)((m >> 13) & 31) * NN + (m & (NN - 1))], v);
        }
        for (unsigned i = gs + tid + 2 * THREADS; i < ge; i += THREADS) { // ~never
            u64 w = LOAD_AU(&se2[i]);
            unsigned m = (unsigned)w;
            float v = __uint_as_float((unsigned)(w >> 32)) * a9[(m >> 13) & 31];
            atomicAdd(&ob[(size_t)((m >> 13) & 31) * NN + (m & (NN - 1))], v);
        }
    }
}

extern "C" void kernel_launch(void* const* d_in, const int* in_sizes, int n_in,
                              void* d_out, int out_size, void* d_ws, size_t ws_size,
                              hipStream_t stream) {
    const float* values = (const float*)d_in[0];
    const float* dem    = (const float*)d_in[1];
    const int*   rows   = (const int*)d_in[2];
    const int*   cols   = (const int*)d_in[3];
    float* out = (float*)d_out;

    u64*      se      = (u64*)d_ws;                       // 2 MB
    u64*      se2     = se + (size_t)EE;                  // 2 MB
    float*    adjF    = (float*)(se2 + (size_t)EE);       // 288 KB
    float*    adj9f   = adjF + 9L * NN;                   // 32 KB
    unsigned* cnt     = (unsigned*)(adj9f + NN);          // 64 KB
    unsigned* cnt2    = cnt + SORTB * NB;                 // 64 KB
    unsigned* bstart  = cnt2 + SORTB * NB;                // 257 (+pad)
    unsigned* gstart  = bstart + 320;                     // 257 (+pad)
    unsigned* flagsC  = gstart + 320;
    unsigned* flagsR  = flagsC + 64;
    unsigned* flagsE  = flagsR + 64;
    unsigned* flagsR2 = flagsE + 64;
    unsigned* flagsK  = flagsR2 + 64;                     // 9*256

    mega<<<NBLK, THREADS, 0, stream>>>(
        values, dem, rows, cols, se, se2, adjF, adj9f, cnt, cnt2,
        bstart, gstart, flagsC, flagsR, flagsE, flagsR2, flagsK, out);
}

// Round 13
// 339.073 us; speedup vs baseline: 1.0523x; 1.0523x over previous
//
#include <hip/hip_runtime.h>

// SparseMinCostFlow — SINGLE mega-dispatch: sorts ∥ 256-wide chain → LDS-img scatter.
// N=8192, E=262144, 10 flow iters, dense NxN fp32 out (256 MB).
//
// r13 = r11 exactly (proven 342.8us). Scatter experiments both regressed:
//  r10 register-assembly: serial dyn-bounded LDS scan, +144us.
//  r12 direct global atomics: 262k cold-line RMWs after zero-stream, +14us.
// r11's LDS-image scatter writes each output line exactly once, full-line —
// empirically optimal. Budget: fills ~204 (harness) + mega ~139 (write floor
// 41 + chain ~30 [9 serial cross-XCD exchanges, latency-bound] + sort/waits).
//
//  blocks 0..63  : col-sort (256 buckets, col>>5) -> flagsE -> chain -> scatter
//  blocks 64..127: row-sort (256 groups, row>>5) -> flagsR2 -> join chain
//  blocks 128..255: park until flagsE -> chain -> scatter
//  chain: all 256 blocks; block owns 32 cols; 1-2 reg edges/thread; per stage
//    adj GATHERS (agent) + 32-col LDS acc + 32-float publish + 256-party barrier.
//  scatter: block streams row-group bid; img double-buffer + raw s_barrier
//    (lgkmcnt only, no vmcnt drain) -> output stores stream at HBM BW.
// Uniform pre-scatter prereqs (r7 lesson): stage-9 256-party barrier (adj9f)
// + all-64 flagsR2 (se2/gstart). All cross-block data agent-scope (ws is
// re-poisoned each iter => plain reads could hit stale 0xAA in L2).
// Grid=256=#CUs, LDS padded => 1 blk/CU, all co-resident (flag barriers).

#define NN 8192
#define EE 262144
#define THREADS 1024
#define SORTB 64                 // blocks per sort team
#define EPB (EE / SORTB)         // 4096 edges per sort block (4/thread)
#define NB 256                   // buckets = groups = chain blocks
#define CPB (NN / NB)            // 32 cols per chain block
#define GROWS 32                 // rows per scatter group
#define NBLK 256
#define MAGIC 0x5CA1AB1Eu        // != 0xAAAAAAAA ws poison, != 0

typedef unsigned long long u64;

#define LOAD_AU(p)    __hip_atomic_load((p),  __ATOMIC_RELAXED, __HIP_MEMORY_SCOPE_AGENT)
#define STORE_AU(p,v) __hip_atomic_store((p), (v), __ATOMIC_RELAXED, __HIP_MEMORY_SCOPE_AGENT)

// raw barrier: drain DS only (NOT vmcnt) — lets global stores stream across rows
#define LBAR() do { asm volatile("s_waitcnt lgkmcnt(0)" ::: "memory"); \
                    __builtin_amdgcn_s_barrier(); \
                    __builtin_amdgcn_sched_barrier(0); } while (0)

// LDS arena: one member live at a time (phases separated by barriers/syncs).
union SM {
    struct { unsigned cnt[SORTB * NB]; unsigned hist[NB]; unsigned bst[NB + 1];
             unsigned offs[NB]; } so;                                  // ~67 KB
    struct { float acc[CPB]; float dem[CPB]; } c;                      // 256 B
    struct { float img[2 * NN]; u64 eL[2048]; } s;                     // 80 KB
    char pad[90112];                                                   // 1 blk/CU
};

// nblk(<=64)-party: set own word + poll (caller __syncthreads first: vmcnt drain).
__device__ __forceinline__ void flag_barrier_n(unsigned* fl, int idx, int tid, int nblk) {
    if (tid == 0) STORE_AU(&fl[idx], MAGIC);
    asm volatile("" ::: "memory");
    if (tid < 64) {
        for (;;) {
            unsigned f = (tid < nblk) ? LOAD_AU(&fl[tid]) : MAGIC;
            if (__all(f == MAGIC)) break;
            __builtin_amdgcn_s_sleep(2);
        }
    }
    asm volatile("" ::: "memory");
    __syncthreads();
}

// 256-party: set own word + poll 4 words/lane.
__device__ __forceinline__ void flag_barrier_256(unsigned* fl, int idx, int tid) {
    if (tid == 0) STORE_AU(&fl[idx], MAGIC);
    asm volatile("" ::: "memory");
    if (tid < 64) {
        for (;;) {
            unsigned a = LOAD_AU(&fl[tid]);
            unsigned b = LOAD_AU(&fl[tid + 64]);
            unsigned c = LOAD_AU(&fl[tid + 128]);
            unsigned d = LOAD_AU(&fl[tid + 192]);
            if (__all(a == MAGIC && b == MAGIC && c == MAGIC && d == MAGIC)) break;
            __builtin_amdgcn_s_sleep(2);
        }
    }
    asm volatile("" ::: "memory");
    __syncthreads();
}

// passive wait on nblk(<=64) words. SLP: s_sleep ticks, compile-time literal.
template <int SLP>
__device__ __forceinline__ void wait_flags_n(unsigned* fl, int tid, int nblk) {
    if (tid < 64) {
        for (;;) {
            unsigned f = (tid < nblk) ? LOAD_AU(&fl[tid]) : MAGIC;
            if (__all(f == MAGIC)) break;
            __builtin_amdgcn_s_sleep(SLP);
        }
    }
    asm volatile("" ::: "memory");
    __syncthreads();
}

__global__ void __launch_bounds__(THREADS) mega(
        const float* __restrict__ values, const float* __restrict__ dem,
        const int* __restrict__ rows, const int* __restrict__ cols,
        u64* __restrict__ se,        // EE col-sorted: row13 | coff5<<13 | v<<32
        u64* __restrict__ se2,       // EE row-sorted: col13 | rl5<<13  | v<<32
        float* __restrict__ adjF,    // 9*NN floats (slots 1..8)
        float* __restrict__ adj9f,   // NN floats (= A10)
        unsigned* __restrict__ cnt,  // SORTB*NB
        unsigned* __restrict__ cnt2, // SORTB*NB
        unsigned* __restrict__ bstart,   // NB+1
        unsigned* __restrict__ gstart,   // NB+1
        unsigned* __restrict__ flagsC, unsigned* __restrict__ flagsR,
        unsigned* __restrict__ flagsE, unsigned* __restrict__ flagsR2,
        unsigned* __restrict__ flagsK,   // 9*NB
        float* __restrict__ out) {
    __shared__ SM sm;
    __shared__ float a9[GROWS];
    const int bid = blockIdx.x, tid = threadIdx.x;

    if (bid < SORTB) {
        // ============ col-sort team: bucket = col>>5 (256 buckets) ============
        if (tid < NB) sm.so.hist[tid] = 0;
        __syncthreads();
        const int4* c4 = (const int4*)(cols + bid * EPB);
        int4 ca = c4[tid];                            // 4 edges/thread
        atomicAdd(&sm.so.hist[ca.x >> 5], 1u);  atomicAdd(&sm.so.hist[ca.y >> 5], 1u);
        atomicAdd(&sm.so.hist[ca.z >> 5], 1u);  atomicAdd(&sm.so.hist[ca.w >> 5], 1u);
        __syncthreads();
        if (tid < NB) STORE_AU(&cnt[bid * NB + tid], sm.so.hist[tid]);
        __syncthreads();                              // drain cnt
        flag_barrier_n(flagsC, bid, tid, SORTB);

        #pragma unroll
        for (int j = 0; j < (SORTB * NB) / THREADS; ++j)
            sm.so.cnt[tid + j * THREADS] = LOAD_AU(&cnt[tid + j * THREADS]);
        __syncthreads();
        if (tid < NB) {
            unsigned t = 0;
            for (int b = 0; b < SORTB; ++b) t += sm.so.cnt[b * NB + tid];
            sm.so.hist[tid] = t;
        }
        __syncthreads();
        if (tid == 0) {
            unsigned run = 0;
            for (int k = 0; k < NB; ++k) { sm.so.bst[k] = run; run += sm.so.hist[k]; }
            sm.so.bst[NB] = run;
        }
        __syncthreads();
        if (tid < NB) {
            unsigned off = sm.so.bst[tid];
            for (int b = 0; b < bid; ++b) off += sm.so.cnt[b * NB + tid];
            sm.so.offs[tid] = off;
        }
        if (bid == 0 && tid <= NB) STORE_AU(&bstart[tid], sm.so.bst[tid]);
        __syncthreads();

        {   // push: meta = row | (col&31)<<13, value hi32
            const int4*   r4 = (const int4*)(rows + bid * EPB);
            const float4* v4 = (const float4*)(values + bid * EPB);
            int4 ra = r4[tid];  float4 va = v4[tid];
            #define PUSHC(R, C, V) do {                                        \
                unsigned dst_ = atomicAdd(&sm.so.offs[(C) >> 5], 1u);          \
                u64 w_ = (unsigned)((R) | (((C) & 31) << 13))                  \
                       | ((u64)__float_as_uint(V) << 32);                      \
                STORE_AU(&se[dst_], w_);                                       \
            } while (0)
            PUSHC(ra.x, ca.x, va.x);  PUSHC(ra.y, ca.y, va.y);
            PUSHC(ra.z, ca.z, va.z);  PUSHC(ra.w, ca.w, va.w);
            #undef PUSHC
        }
        __syncthreads();                              // drain se + bstart
        flag_barrier_n(flagsE, bid, tid, SORTB);      // col-sort complete
    } else if (bid < 2 * SORTB) {
        // ============ row-sort team: group = row>>5 (256 groups) ============
        const int b2 = bid - SORTB;
        if (tid < NB) sm.so.hist[tid] = 0;
        __syncthreads();
        const int4* r4 = (const int4*)(rows + b2 * EPB);
        int4 ra = r4[tid];
        atomicAdd(&sm.so.hist[ra.x >> 5], 1u);  atomicAdd(&sm.so.hist[ra.y >> 5], 1u);
        atomicAdd(&sm.so.hist[ra.z >> 5], 1u);  atomicAdd(&sm.so.hist[ra.w >> 5], 1u);
        __syncthreads();
        if (tid < NB) STORE_AU(&cnt2[b2 * NB + tid], sm.so.hist[tid]);
        __syncthreads();
        flag_barrier_n(flagsR, b2, tid, SORTB);

        #pragma unroll
        for (int j = 0; j < (SORTB * NB) / THREADS; ++j)
            sm.so.cnt[tid + j * THREADS] = LOAD_AU(&cnt2[tid + j * THREADS]);
        __syncthreads();
        if (tid < NB) {
            unsigned t = 0;
            for (int b = 0; b < SORTB; ++b) t += sm.so.cnt[b * NB + tid];
            sm.so.hist[tid] = t;
        }
        __syncthreads();
        if (tid == 0) {
            unsigned run = 0;
            for (int k = 0; k < NB; ++k) { sm.so.bst[k] = run; run += sm.so.hist[k]; }
            sm.so.bst[NB] = run;
        }
        __syncthreads();
        if (tid < NB) {
            unsigned off = sm.so.bst[tid];
            for (int b = 0; b < b2; ++b) off += sm.so.cnt[b * NB + tid];
            sm.so.offs[tid] = off;
        }
        if (b2 == 0 && tid <= NB) STORE_AU(&gstart[tid], sm.so.bst[tid]);
        __syncthreads();

        {   // push: meta = col | (row&31)<<13, value hi32
            const int4*   c4 = (const int4*)(cols + b2 * EPB);
            const float4* v4 = (const float4*)(values + b2 * EPB);
            int4 ca = c4[tid];  float4 va = v4[tid];
            #define PUSHR(R, C, V) do {                                        \
                unsigned dst_ = atomicAdd(&sm.so.offs[(R) >> 5], 1u);          \
                u64 w_ = (unsigned)((C) | (((R) & 31) << 13))                  \
                       | ((u64)__float_as_uint(V) << 32);                      \
                STORE_AU(&se2[dst_], w_);                                      \
            } while (0)
            PUSHR(ra.x, ca.x, va.x);  PUSHR(ra.y, ca.y, va.y);
            PUSHR(ra.z, ca.z, va.z);  PUSHR(ra.w, ca.w, va.w);
            #undef PUSHR
        }
        __syncthreads();                              // drain se2 + gstart
        if (tid == 0) STORE_AU(&flagsR2[b2], MAGIC);
        asm volatile("" ::: "memory");
        wait_flags_n<4>(flagsE, tid, SORTB);          // then join the chain
    } else {
        // ============ parked until col-sort done ============
        wait_flags_n<8>(flagsE, tid, SORTB);
    }

    // ================= chain: ALL 256 blocks, block owns bucket `bid` =======
    const int bs = (int)LOAD_AU(&bstart[bid]);
    const int be = (int)LOAD_AU(&bstart[bid + 1]);
    const int ne = be - bs;
    u64 e0 = 0, e1 = 0;                               // ~1024 edges -> 1-2 regs
    if (tid < ne)           e0 = LOAD_AU(&se[bs + tid]);
    if (THREADS + tid < ne) e1 = LOAD_AU(&se[bs + THREADS + tid]);
    if (tid < CPB) sm.c.dem[tid] = dem[bid * CPB + tid];

    for (int s = 1; s <= 9; ++s) {
        if (tid < CPB) sm.c.acc[tid] = 0.f;
        __syncthreads();

        #define EDGE(W) do {                                                   \
            unsigned m_ = (unsigned)(W);                                       \
            float v_ = __uint_as_float((unsigned)((W) >> 32));                 \
            int r_ = m_ & (NN - 1);                                            \
            float a_ = (s == 1) ? fmaxf(-dem[r_], 0.f)                         \
                                : LOAD_AU(&adjF[(size_t)(s - 1) * NN + r_]);   \
            atomicAdd(&sm.c.acc[(m_ >> 13) & 31], v_ * a_);                    \
        } while (0)
        if (tid < ne)           EDGE(e0);
        if (THREADS + tid < ne) EDGE(e1);
        for (int i = bs + 2 * THREADS + tid; i < be; i += THREADS) {  // ~never
            u64 w = LOAD_AU(&se[i]);
            EDGE(w);
        }
        #undef EDGE
        __syncthreads();

        if (tid < CPB) {
            float r = fmaxf(sm.c.acc[tid] - sm.c.dem[tid], 0.f);
            if (s < 9) STORE_AU(&adjF[(size_t)s * NN + bid * CPB + tid], r);
            else       STORE_AU(&adj9f[bid * CPB + tid], r);
        }
        __syncthreads();                              // drain publish
        flag_barrier_256(flagsK + (s - 1) * NB, bid, tid);
    }
    // stage-9 barrier == all adj9f visible. Uniform last prereq:
    wait_flags_n<2>(flagsR2, tid, SORTB);             // se2/gstart (long ready)

    // ======= scatter: block streams row-group `bid`, img double-buffered ====
    {
        const int g = bid;
        const unsigned gs = LOAD_AU(&gstart[g]), ge = LOAD_AU(&gstart[g + 1]);
        const unsigned n = ge - gs;
        const unsigned ncp = n < 2048u ? n : 2048u;
        if (tid < GROWS) a9[tid] = LOAD_AU(&adj9f[g * GROWS + tid]);
        __syncthreads();                              // a9 + LDS transition

        for (unsigned i = tid; i < ncp; i += THREADS) {   // premultiply
            u64 w = LOAD_AU(&se2[gs + i]);
            unsigned m = (unsigned)w;
            float v = __uint_as_float((unsigned)(w >> 32));
            sm.s.eL[i] = (u64)m | ((u64)__float_as_uint(v * a9[(m >> 13) & 31]) << 32);
        }
        __syncthreads();

        const float4 z4 = make_float4(0.f, 0.f, 0.f, 0.f);
        for (int r = 0; r < GROWS; ++r) {
            float* im = sm.s.img + (r & 1) * NN;
            ((float4*)im)[tid]        = z4;           // zero 32KB image
            ((float4*)im)[tid + 1024] = z4;
            LBAR();
            for (unsigned i = tid; i < ncp; i += THREADS) {
                u64 w = sm.s.eL[i];
                unsigned m = (unsigned)w;
                if (((m >> 13) & 31) == (unsigned)r)
                    atomicAdd(&im[m & (NN - 1)], __uint_as_float((unsigned)(w >> 32)));
            }
            for (unsigned i = 2048u + tid; i < n; i += THREADS) {   // ~never
                u64 w = LOAD_AU(&se2[gs + i]);
                unsigned m = (unsigned)w;
                if (((m >> 13) & 31) == (unsigned)r)
                    atomicAdd(&im[m & (NN - 1)],
                              __uint_as_float((unsigned)(w >> 32)) * a9[r]);
            }
            LBAR();
            float4 w0 = ((const float4*)im)[tid];     // ds_read, lgkm-waited
            float4 w1 = ((const float4*)im)[tid + 1024];
            float4* o4 = (float4*)(out + (size_t)(g * GROWS + r) * NN);
            o4[tid]        = w0;                      // stores stream (no drain)
            o4[tid + 1024] = w1;
        }
    }
}

extern "C" void kernel_launch(void* const* d_in, const int* in_sizes, int n_in,
                              void* d_out, int out_size, void* d_ws, size_t ws_size,
                              hipStream_t stream) {
    const float* values = (const float*)d_in[0];
    const float* dem    = (const float*)d_in[1];
    const int*   rows   = (const int*)d_in[2];
    const int*   cols   = (const int*)d_in[3];
    float* out = (float*)d_out;

    u64*      se      = (u64*)d_ws;                       // 2 MB
    u64*      se2     = se + (size_t)EE;                  // 2 MB
    float*    adjF    = (float*)(se2 + (size_t)EE);       // 288 KB
    float*    adj9f   = adjF + 9L * NN;                   // 32 KB
    unsigned* cnt     = (unsigned*)(adj9f + NN);          // 64 KB
    unsigned* cnt2    = cnt + SORTB * NB;                 // 64 KB
    unsigned* bstart  = cnt2 + SORTB * NB;                // 257 (+pad)
    unsigned* gstart  = bstart + 320;                     // 257 (+pad)
    unsigned* flagsC  = gstart + 320;
    unsigned* flagsR  = flagsC + 64;
    unsigned* flagsE  = flagsR + 64;
    unsigned* flagsR2 = flagsE + 64;
    unsigned* flagsK  = flagsR2 + 64;                     // 9*256

    mega<<<NBLK, THREADS, 0, stream>>>(
        values, dem, rows, cols, se, se2, adjF, adj9f, cnt, cnt2,
        bstart, gstart, flagsC, flagsR, flagsE, flagsR2, flagsK, out);
}

// Round 14
// 309.033 us; speedup vs baseline: 1.1545x; 1.0972x over previous
//
#include <hip/hip_runtime.h>

// SparseMinCostFlow — SINGLE mega-dispatch: sorts ∥ DATAFLOW chain → LDS-img scatter.
// N=8192, E=262144, 10 flow iters, dense NxN fp32 out (256 MB).
//
// r14: chain barriers removed — consumers poll the published adjF words
// DIRECTLY for the ws-poison sentinel (0xAAAAAAAA is negative as f32; all
// published values are relu outputs >= 0, never poison). One MALL round-trip
// per dependency instead of flag-store + flag-poll + data-load; each block
// proceeds when ITS gather rows are ready. Deadlock-free by induction
// (stage 1 dep-free; each slot written once; per-stage distinct slots).
// Scatter polls its 32 adj9f words the same way (replaces stage-9 barrier;
// per-word dataflow is watertight vs the r7 tripwire class).
// Everything else = r13 (proven 339-343us): 64-block sort teams, LDS-image
// scatter (each out line written once, full-line; beat both alternatives).
//
//  blocks 0..63  : col-sort (256 buckets, col>>5) -> flagsE -> chain -> scatter
//  blocks 64..127: row-sort (256 groups, row>>5) -> flagsR2 -> join chain
//  blocks 128..255: park until flagsE -> chain -> scatter
// All cross-block data agent-scope (ws re-poisoned each iter => plain reads
// could hit stale 0xAA in L2). Grid=256=#CUs, LDS padded => 1 blk/CU.

#define NN 8192
#define EE 262144
#define THREADS 1024
#define SORTB 64                 // blocks per sort team
#define EPB (EE / SORTB)         // 4096 edges per sort block (4/thread)
#define NB 256                   // buckets = groups = chain blocks
#define CPB (NN / NB)            // 32 cols per chain block
#define GROWS 32                 // rows per scatter group
#define NBLK 256
#define MAGIC 0x5CA1AB1Eu        // != 0xAAAAAAAA ws poison, != 0
#define POISON 0xAAAAAAAAu       // harness ws fill; f32-negative => never a relu output

typedef unsigned long long u64;

#define LOAD_AU(p)    __hip_atomic_load((p),  __ATOMIC_RELAXED, __HIP_MEMORY_SCOPE_AGENT)
#define STORE_AU(p,v) __hip_atomic_store((p), (v), __ATOMIC_RELAXED, __HIP_MEMORY_SCOPE_AGENT)

// raw barrier: drain DS only (NOT vmcnt) — lets global stores stream across rows
#define LBAR() do { asm volatile("s_waitcnt lgkmcnt(0)" ::: "memory"); \
                    __builtin_amdgcn_s_barrier(); \
                    __builtin_amdgcn_sched_barrier(0); } while (0)

// LDS arena: one member live at a time (phases separated by barriers/syncs).
union SM {
    struct { unsigned cnt[SORTB * NB]; unsigned hist[NB]; unsigned bst[NB + 1];
             unsigned offs[NB]; } so;                                  // ~67 KB
    struct { float acc[CPB]; float dem[CPB]; } c;                      // 256 B
    struct { float img[2 * NN]; u64 eL[2048]; } s;                     // 80 KB
    char pad[90112];                                                   // 1 blk/CU
};

// nblk(<=64)-party: set own word + poll (caller __syncthreads first: vmcnt drain).
__device__ __forceinline__ void flag_barrier_n(unsigned* fl, int idx, int tid, int nblk) {
    if (tid == 0) STORE_AU(&fl[idx], MAGIC);
    asm volatile("" ::: "memory");
    if (tid < 64) {
        for (;;) {
            unsigned f = (tid < nblk) ? LOAD_AU(&fl[tid]) : MAGIC;
            if (__all(f == MAGIC)) break;
            __builtin_amdgcn_s_sleep(2);
        }
    }
    asm volatile("" ::: "memory");
    __syncthreads();
}

// passive wait on nblk(<=64) words. SLP: s_sleep ticks, compile-time literal.
template <int SLP>
__device__ __forceinline__ void wait_flags_n(unsigned* fl, int tid, int nblk) {
    if (tid < 64) {
        for (;;) {
            unsigned f = (tid < nblk) ? LOAD_AU(&fl[tid]) : MAGIC;
            if (__all(f == MAGIC)) break;
            __builtin_amdgcn_s_sleep(SLP);
        }
    }
    asm volatile("" ::: "memory");
    __syncthreads();
}

// dataflow read: spin until the published word is non-poison.
__device__ __forceinline__ float poll_f32(const float* p) {
    unsigned u;
    for (;;) {
        u = LOAD_AU((const unsigned*)p);
        if (u != POISON) break;
        __builtin_amdgcn_s_sleep(1);
    }
    return __uint_as_float(u);
}

__global__ void __launch_bounds__(THREADS) mega(
        const float* __restrict__ values, const float* __restrict__ dem,
        const int* __restrict__ rows, const int* __restrict__ cols,
        u64* __restrict__ se,        // EE col-sorted: row13 | coff5<<13 | v<<32
        u64* __restrict__ se2,       // EE row-sorted: col13 | rl5<<13  | v<<32
        float* __restrict__ adjF,    // 9*NN floats (slots 1..8)
        float* __restrict__ adj9f,   // NN floats (= A10)
        unsigned* __restrict__ cnt,  // SORTB*NB
        unsigned* __restrict__ cnt2, // SORTB*NB
        unsigned* __restrict__ bstart,   // NB+1
        unsigned* __restrict__ gstart,   // NB+1
        unsigned* __restrict__ flagsC, unsigned* __restrict__ flagsR,
        unsigned* __restrict__ flagsE, unsigned* __restrict__ flagsR2,
        float* __restrict__ out) {
    __shared__ SM sm;
    __shared__ float a9[GROWS];
    const int bid = blockIdx.x, tid = threadIdx.x;

    if (bid < SORTB) {
        // ============ col-sort team: bucket = col>>5 (256 buckets) ============
        if (tid < NB) sm.so.hist[tid] = 0;
        __syncthreads();
        const int4* c4 = (const int4*)(cols + bid * EPB);
        int4 ca = c4[tid];                            // 4 edges/thread
        atomicAdd(&sm.so.hist[ca.x >> 5], 1u);  atomicAdd(&sm.so.hist[ca.y >> 5], 1u);
        atomicAdd(&sm.so.hist[ca.z >> 5], 1u);  atomicAdd(&sm.so.hist[ca.w >> 5], 1u);
        __syncthreads();
        if (tid < NB) STORE_AU(&cnt[bid * NB + tid], sm.so.hist[tid]);
        __syncthreads();                              // drain cnt
        flag_barrier_n(flagsC, bid, tid, SORTB);

        #pragma unroll
        for (int j = 0; j < (SORTB * NB) / THREADS; ++j)
            sm.so.cnt[tid + j * THREADS] = LOAD_AU(&cnt[tid + j * THREADS]);
        __syncthreads();
        if (tid < NB) {
            unsigned t = 0;
            for (int b = 0; b < SORTB; ++b) t += sm.so.cnt[b * NB + tid];
            sm.so.hist[tid] = t;
        }
        __syncthreads();
        if (tid == 0) {
            unsigned run = 0;
            for (int k = 0; k < NB; ++k) { sm.so.bst[k] = run; run += sm.so.hist[k]; }
            sm.so.bst[NB] = run;
        }
        __syncthreads();
        if (tid < NB) {
            unsigned off = sm.so.bst[tid];
            for (int b = 0; b < bid; ++b) off += sm.so.cnt[b * NB + tid];
            sm.so.offs[tid] = off;
        }
        if (bid == 0 && tid <= NB) STORE_AU(&bstart[tid], sm.so.bst[tid]);
        __syncthreads();

        {   // push: meta = row | (col&31)<<13, value hi32
            const int4*   r4 = (const int4*)(rows + bid * EPB);
            const float4* v4 = (const float4*)(values + bid * EPB);
            int4 ra = r4[tid];  float4 va = v4[tid];
            #define PUSHC(R, C, V) do {                                        \
                unsigned dst_ = atomicAdd(&sm.so.offs[(C) >> 5], 1u);          \
                u64 w_ = (unsigned)((R) | (((C) & 31) << 13))                  \
                       | ((u64)__float_as_uint(V) << 32);                      \
                STORE_AU(&se[dst_], w_);                                       \
            } while (0)
            PUSHC(ra.x, ca.x, va.x);  PUSHC(ra.y, ca.y, va.y);
            PUSHC(ra.z, ca.z, va.z);  PUSHC(ra.w, ca.w, va.w);
            #undef PUSHC
        }
        __syncthreads();                              // drain se + bstart
        flag_barrier_n(flagsE, bid, tid, SORTB);      // col-sort complete
    } else if (bid < 2 * SORTB) {
        // ============ row-sort team: group = row>>5 (256 groups) ============
        const int b2 = bid - SORTB;
        if (tid < NB) sm.so.hist[tid] = 0;
        __syncthreads();
        const int4* r4 = (const int4*)(rows + b2 * EPB);
        int4 ra = r4[tid];
        atomicAdd(&sm.so.hist[ra.x >> 5], 1u);  atomicAdd(&sm.so.hist[ra.y >> 5], 1u);
        atomicAdd(&sm.so.hist[ra.z >> 5], 1u);  atomicAdd(&sm.so.hist[ra.w >> 5], 1u);
        __syncthreads();
        if (tid < NB) STORE_AU(&cnt2[b2 * NB + tid], sm.so.hist[tid]);
        __syncthreads();
        flag_barrier_n(flagsR, b2, tid, SORTB);

        #pragma unroll
        for (int j = 0; j < (SORTB * NB) / THREADS; ++j)
            sm.so.cnt[tid + j * THREADS] = LOAD_AU(&cnt2[tid + j * THREADS]);
        __syncthreads();
        if (tid < NB) {
            unsigned t = 0;
            for (int b = 0; b < SORTB; ++b) t += sm.so.cnt[b * NB + tid];
            sm.so.hist[tid] = t;
        }
        __syncthreads();
        if (tid == 0) {
            unsigned run = 0;
            for (int k = 0; k < NB; ++k) { sm.so.bst[k] = run; run += sm.so.hist[k]; }
            sm.so.bst[NB] = run;
        }
        __syncthreads();
        if (tid < NB) {
            unsigned off = sm.so.bst[tid];
            for (int b = 0; b < b2; ++b) off += sm.so.cnt[b * NB + tid];
            sm.so.offs[tid] = off;
        }
        if (b2 == 0 && tid <= NB) STORE_AU(&gstart[tid], sm.so.bst[tid]);
        __syncthreads();

        {   // push: meta = col | (row&31)<<13, value hi32
            const int4*   c4 = (const int4*)(cols + b2 * EPB);
            const float4* v4 = (const float4*)(values + b2 * EPB);
            int4 ca = c4[tid];  float4 va = v4[tid];
            #define PUSHR(R, C, V) do {                                        \
                unsigned dst_ = atomicAdd(&sm.so.offs[(R) >> 5], 1u);          \
                u64 w_ = (unsigned)((C) | (((R) & 31) << 13))                  \
                       | ((u64)__float_as_uint(V) << 32);                      \
                STORE_AU(&se2[dst_], w_);                                      \
            } while (0)
            PUSHR(ra.x, ca.x, va.x);  PUSHR(ra.y, ca.y, va.y);
            PUSHR(ra.z, ca.z, va.z);  PUSHR(ra.w, ca.w, va.w);
            #undef PUSHR
        }
        __syncthreads();                              // drain se2 + gstart
        if (tid == 0) STORE_AU(&flagsR2[b2], MAGIC);
        asm volatile("" ::: "memory");
        wait_flags_n<4>(flagsE, tid, SORTB);          // then join the chain
    } else {
        // ============ parked until col-sort done ============
        wait_flags_n<8>(flagsE, tid, SORTB);
    }

    // ========== chain: ALL 256 blocks, DATAFLOW (no stage barriers) =========
    const int bs = (int)LOAD_AU(&bstart[bid]);
    const int be = (int)LOAD_AU(&bstart[bid + 1]);
    const int ne = be - bs;
    u64 e0 = 0, e1 = 0;                               // ~1024 edges -> 1-2 regs
    if (tid < ne)           e0 = LOAD_AU(&se[bs + tid]);
    if (THREADS + tid < ne) e1 = LOAD_AU(&se[bs + THREADS + tid]);
    if (tid < CPB) sm.c.dem[tid] = dem[bid * CPB + tid];

    for (int s = 1; s <= 9; ++s) {
        if (tid < CPB) sm.c.acc[tid] = 0.f;
        __syncthreads();

        // adj_{s} gather: s==1 from dem; else POLL published word (data=flag)
        #define EDGE(W) do {                                                   \
            unsigned m_ = (unsigned)(W);                                       \
            float v_ = __uint_as_float((unsigned)((W) >> 32));                 \
            int r_ = m_ & (NN - 1);                                            \
            float a_ = (s == 1) ? fmaxf(-dem[r_], 0.f)                         \
                                : poll_f32(&adjF[(size_t)(s - 1) * NN + r_]);  \
            atomicAdd(&sm.c.acc[(m_ >> 13) & 31], v_ * a_);                    \
        } while (0)
        if (tid < ne)           EDGE(e0);
        if (THREADS + tid < ne) EDGE(e1);
        for (int i = bs + 2 * THREADS + tid; i < be; i += THREADS) {  // ~never
            u64 w = LOAD_AU(&se[i]);
            EDGE(w);
        }
        #undef EDGE
        __syncthreads();

        if (tid < CPB) {                              // publish: data IS the flag
            float r = fmaxf(sm.c.acc[tid] - sm.c.dem[tid], 0.f);
            if (s < 9) STORE_AU(&adjF[(size_t)s * NN + bid * CPB + tid], r);
            else       STORE_AU(&adj9f[bid * CPB + tid], r);
        }
        // no barrier: only tid<CPB touch acc between the two syncthreads
    }
    wait_flags_n<2>(flagsR2, tid, SORTB);             // se2/gstart visible

    // ======= scatter: block streams row-group `bid`, img double-buffered ====
    {
        const int g = bid;
        const unsigned gs = LOAD_AU(&gstart[g]), ge = LOAD_AU(&gstart[g + 1]);
        const unsigned n = ge - gs;
        const unsigned ncp = n < 2048u ? n : 2048u;
        if (tid < GROWS) a9[tid] = poll_f32(&adj9f[g * GROWS + tid]);  // dataflow
        __syncthreads();                              // a9 + LDS transition

        for (unsigned i = tid; i < ncp; i += THREADS) {   // premultiply
            u64 w = LOAD_AU(&se2[gs + i]);
            unsigned m = (unsigned)w;
            float v = __uint_as_float((unsigned)(w >> 32));
            sm.s.eL[i] = (u64)m | ((u64)__float_as_uint(v * a9[(m >> 13) & 31]) << 32);
        }
        __syncthreads();

        const float4 z4 = make_float4(0.f, 0.f, 0.f, 0.f);
        for (int r = 0; r < GROWS; ++r) {
            float* im = sm.s.img + (r & 1) * NN;
            ((float4*)im)[tid]        = z4;           // zero 32KB image
            ((float4*)im)[tid + 1024] = z4;
            LBAR();
            for (unsigned i = tid; i < ncp; i += THREADS) {
                u64 w = sm.s.eL[i];
                unsigned m = (unsigned)w;
                if (((m >> 13) & 31) == (unsigned)r)
                    atomicAdd(&im[m & (NN - 1)], __uint_as_float((unsigned)(w >> 32)));
            }
            for (unsigned i = 2048u + tid; i < n; i += THREADS) {   // ~never
                u64 w = LOAD_AU(&se2[gs + i]);
                unsigned m = (unsigned)w;
                if (((m >> 13) & 31) == (unsigned)r)
                    atomicAdd(&im[m & (NN - 1)],
                              __uint_as_float((unsigned)(w >> 32)) * a9[r]);
            }
            LBAR();
            float4 w0 = ((const float4*)im)[tid];     // ds_read, lgkm-waited
            float4 w1 = ((const float4*)im)[tid + 1024];
            float4* o4 = (float4*)(out + (size_t)(g * GROWS + r) * NN);
            o4[tid]        = w0;                      // stores stream (no drain)
            o4[tid + 1024] = w1;
        }
    }
}

extern "C" void kernel_launch(void* const* d_in, const int* in_sizes, int n_in,
                              void* d_out, int out_size, void* d_ws, size_t ws_size,
                              hipStream_t stream) {
    const float* values = (const float*)d_in[0];
    const float* dem    = (const float*)d_in[1];
    const int*   rows   = (const int*)d_in[2];
    const int*   cols   = (const int*)d_in[3];
    float* out = (float*)d_out;

    u64*      se      = (u64*)d_ws;                       // 2 MB
    u64*      se2     = se + (size_t)EE;                  // 2 MB
    float*    adjF    = (float*)(se2 + (size_t)EE);       // 288 KB
    float*    adj9f   = adjF + 9L * NN;                   // 32 KB
    unsigned* cnt     = (unsigned*)(adj9f + NN);          // 64 KB
    unsigned* cnt2    = cnt + SORTB * NB;                 // 64 KB
    unsigned* bstart  = cnt2 + SORTB * NB;                // 257 (+pad)
    unsigned* gstart  = bstart + 320;                     // 257 (+pad)
    unsigned* flagsC  = gstart + 320;
    unsigned* flagsR  = flagsC + 64;
    unsigned* flagsE  = flagsR + 64;
    unsigned* flagsR2 = flagsE + 64;

    mega<<<NBLK, THREADS, 0, stream>>>(
        values, dem, rows, cols, se, se2, adjF, adj9f, cnt, cnt2,
        bstart, gstart, flagsC, flagsR, flagsE, flagsR2, out);
}